// Round 2
// baseline (1213.521 us; speedup 1.0000x reference)
//
#include <hip/hip_runtime.h>
#include <hip/hip_cooperative_groups.h>
#include <math.h>

namespace cg = cooperative_groups;

#define B_  64
#define D_  256
#define H_  512
#define N_  16384
#define M_  64
#define EPS_ 1e-4f

#define NBLK 256
#define NTHR 512
#define CHUNK (N_ / 4)   // rows per block in streaming phases (4 blocks per batch)

struct Args {
  const float *inp, *h_tm1, *c_tm1, *read_tm1, *write_tm1, *memory;
  const float *W_ih, *b_ih, *W_hh, *b_hh;
  const float *W_rk, *b_rk, *W_wk, *b_wk;
  const float *W_rc, *b_rc, *W_wc, *b_wc;
  const float *W_rs, *b_rs, *W_ws, *b_ws;
  const float *W_w, *b_w;
  float *h_out, *c_out, *rhead, *whead, *Mout;
  float *gates, *rk, *wk, *M_read, *e_buf, *a_buf, *rs, *wss;
  float *rbeta, *rg, *rgamma, *rnk, *wbeta, *wg, *wgamma, *wnk;
  float *Pmax, *Psum, *Psum2;
};

union Smem {
  float raw[256];                          // head_params GEMV rows
  float red[16];                           // block reduce scratch (8 waves, m+s)
  float4 part4[128];                       // M_read reduce (8 waves x 16)
  float cvinter[CHUNK + 2];                // inter chunk + 2-left halo for conv
  // gates GEMM staging: X[k][b] (64x64, pad 68), W[k][j] (64x128, pad 132).
  // NOTE: k-major with row-padded second dim — W[64][132], indexed W[k][row].
  struct { float X[64][68]; float W[64][132]; } g;   // 51.2 KB
};

__device__ __forceinline__ float sigmoidf_(float x) { return 1.0f / (1.0f + expf(-x)); }

// block-wide sum of v -> *out written by tid 0 (red = 16-float LDS scratch)
__device__ __forceinline__ void block_sum_to(float v, float* red, float* out) {
    for (int off = 32; off >= 1; off >>= 1) v += __shfl_xor(v, off);
    const int wid = threadIdx.x >> 6;
    if ((threadIdx.x & 63) == 0) red[wid] = v;
    __syncthreads();
    if (threadIdx.x == 0) {
        float s = red[0];
        #pragma unroll
        for (int i = 1; i < 8; ++i) s += red[i];
        *out = s;
    }
    __syncthreads();
}

// block-wide online-softmax pair combine; (m,s) neutral element = (-1e30, 0)
__device__ __forceinline__ void block_pair_to(float m, float s, float* red,
                                              float* outm, float* outs) {
    for (int off = 32; off >= 1; off >>= 1) {
        float m2 = __shfl_xor(m, off), s2 = __shfl_xor(s, off);
        float mn = fmaxf(m, m2);
        s = s * expf(m - mn) + s2 * expf(m2 - mn);
        m = mn;
    }
    const int wid = threadIdx.x >> 6;
    if ((threadIdx.x & 63) == 0) { red[wid] = m; red[8 + wid] = s; }
    __syncthreads();
    if (threadIdx.x == 0) {
        float M = red[0], S = red[8];
        for (int i = 1; i < 8; ++i) {
            float mn = fmaxf(M, red[i]);
            S = S * expf(M - mn) + red[8 + i] * expf(red[i] - mn);
            M = mn;
        }
        *outm = M; *outs = S;
    }
    __syncthreads();
}

// wave-per-row GEMV head params (8 waves, 512 threads), block handles batch b
__device__ void head_params(const float* h,
    const float* Wk, const float* bk, const float* Wc, const float* bc,
    const float* Ws, const float* bs, const float* Ww, const float* bw,
    int with_w, int b,
    float* k_out, float* nk_out, float* s_out,
    float* beta_out, float* g_out, float* gamma_out,
    float* e_out, float* a_out, float* raw)
{
    const int tid = threadIdx.x;
    const int lane = tid & 63;
    const int wid = tid >> 6;
    float h8[8];
    #pragma unroll
    for (int j = 0; j < 8; ++j) h8[j] = h[b * H_ + lane + 64 * j];
    const int count = with_w ? 198 : 70;
    for (int r = wid; r < count; r += 8) {
        const float* wrow; float bias;
        if (r < 64)      { wrow = Wk + r * H_;          bias = bk[r]; }
        else if (r < 67) { wrow = Wc + (r - 64) * H_;   bias = bc[r - 64]; }
        else if (r < 70) { wrow = Ws + (r - 67) * H_;   bias = bs[r - 67]; }
        else             { wrow = Ww + (r - 70) * H_;   bias = bw[r - 70]; }
        float acc = 0.f;
        #pragma unroll
        for (int j = 0; j < 8; ++j) acc += wrow[lane + 64 * j] * h8[j];
        for (int off = 32; off >= 1; off >>= 1) acc += __shfl_xor(acc, off);
        if (lane == 0) raw[r] = acc + bias;
    }
    __syncthreads();
    if (tid < 64) {
        float kv = tanhf(raw[tid]);
        k_out[b * 64 + tid] = kv;
        float sq = kv * kv;
        for (int off = 32; off >= 1; off >>= 1) sq += __shfl_xor(sq, off);
        if (tid == 0) nk_out[b] = sqrtf(sq) + EPS_;
    } else if (tid == 64) {
        beta_out[b]  = fmaxf(raw[64], 0.f) + EPS_;
        g_out[b]     = sigmoidf_(raw[65]);
        gamma_out[b] = fmaxf(raw[66], 0.f) + 1.f + EPS_;
    } else if (tid == 65) {
        float s0 = raw[67], s1 = raw[68], s2 = raw[69];
        float mx = fmaxf(s0, fmaxf(s1, s2));
        float e0 = expf(s0 - mx), e1 = expf(s1 - mx), e2 = expf(s2 - mx);
        float inv = 1.f / (e0 + e1 + e2);
        s_out[b * 3 + 0] = e0 * inv;
        s_out[b * 3 + 1] = e1 * inv;
        s_out[b * 3 + 2] = e2 * inv;
    }
    if (with_w && tid >= 128 && tid < 192) {
        int m = tid - 128;
        e_out[b * 64 + m] = sigmoidf_(raw[70 + m]);
        a_out[b * 64 + m] = raw[134 + m];
    }
    __syncthreads();
}

__global__ __launch_bounds__(NTHR) void ntm_mega(Args p)
{
    cg::grid_group grid = cg::this_grid();
    __shared__ Smem sm;

    const int blk  = blockIdx.x;
    const int tid  = threadIdx.x;
    const int m16  = tid & 15;
    const int rgrp = tid >> 4;            // 0..31 (row group in streaming phases)
    const int b    = blk >> 2;            // batch for streaming phases
    const int cc   = blk & 3;             // chunk 0..3
    const int n0   = cc * CHUNK;
    const size_t bbase = (size_t)b * N_;

    float* xbuf  = p.Mout + (size_t)B_ * N_;   // scratch, dead before P13
    float* nMbuf = p.Mout;                     // scratch, dead before P13

    // ---- P0: read-head params (blocks 0..63) | zero gates + M_read (rest)
    if (blk < 64) {
        head_params(p.h_tm1, p.W_rk, p.b_rk, p.W_rc, p.b_rc, p.W_rs, p.b_rs,
                    nullptr, nullptr, 0, blk,
                    p.rk, p.rnk, p.rs, p.rbeta, p.rg, p.rgamma, nullptr, nullptr, sm.raw);
    } else {
        for (int i = (blk - 64) * NTHR + tid; i < B_ * 4 * H_; i += 192 * NTHR)
            p.gates[i] = 0.f;
        if (blk == 64)
            for (int i = tid; i < B_ * M_; i += NTHR) p.M_read[i] = 0.f;
    }
    grid.sync();

    // ---- P1: memory pass 1 -> x (content arg), nM, online (max,sum) pair
    {
        const float4 k4  = ((const float4*)(p.rk + b * 64))[m16];
        const float beta = p.rbeta[b], nk = p.rnk[b];
        float lm = -1e30f, ls = 0.f;
        #pragma unroll 4
        for (int it = 0; it < CHUNK / 32; ++it) {
            const int n = n0 + it * 32 + rgrp;
            const float4 m4 = ((const float4*)(p.memory + (bbase + n) * 64))[m16];
            float d  = m4.x * k4.x + m4.y * k4.y + m4.z * k4.z + m4.w * k4.w;
            float sq = m4.x * m4.x + m4.y * m4.y + m4.z * m4.z + m4.w * m4.w;
            for (int off = 8; off >= 1; off >>= 1) {
                d += __shfl_xor(d, off); sq += __shfl_xor(sq, off);
            }
            if (m16 == 0) {
                float nMv = sqrtf(sq) + EPS_;
                float x = beta * d / (nMv * nk);
                xbuf[bbase + n]  = x;
                nMbuf[bbase + n] = nMv;
                float mn = fmaxf(lm, x);
                ls = ls * expf(lm - mn) + expf(x - mn);
                lm = mn;
            }
        }
        block_pair_to(lm, ls, sm.red, &p.Pmax[blk], &p.Psum[blk]);
    }
    grid.sync();

    // ---- P3: inter (LDS w/ halo) -> conv -> sharpen -> sharp in whead slot
    {
        float Mx = -1e30f, Sx = 0.f;
        #pragma unroll
        for (int c2 = 0; c2 < 4; ++c2) {
            float m = p.Pmax[b * 4 + c2], s = p.Psum[b * 4 + c2];
            float mn = fmaxf(Mx, m);
            Sx = Sx * expf(Mx - mn) + s * expf(m - mn);
            Mx = mn;
        }
        const float inv = 1.f / Sx, gmax = Mx;
        const float g = p.rg[b], gamma = p.rgamma[b];
        const float s0 = p.rs[b * 3 + 0], s1 = p.rs[b * 3 + 1], s2 = p.rs[b * 3 + 2];
        #pragma unroll
        for (int j = 0; j < CHUNK / NTHR; ++j) {
            const int i = j * NTHR + tid;
            const int n = n0 + i;
            sm.cvinter[i + 2] = g * expf(xbuf[bbase + n] - gmax) * inv
                              + (1.f - g) * p.read_tm1[bbase + n];
        }
        if (tid < 2) {
            const int n = (n0 + N_ - 2 + tid) & (N_ - 1);
            sm.cvinter[tid] = g * expf(xbuf[bbase + n] - gmax) * inv
                            + (1.f - g) * p.read_tm1[bbase + n];
        }
        __syncthreads();
        float lsum = 0.f;
        #pragma unroll
        for (int j = 0; j < CHUNK / NTHR; ++j) {
            const int i = j * NTHR + tid;
            const float conv = s2 * sm.cvinter[i + 2] + s1 * sm.cvinter[i + 1]
                             + s0 * sm.cvinter[i];
            const float v = powf(fmaxf(conv, 1e-8f), gamma);
            p.whead[bbase + n0 + i] = v;      // sharp_r (whead slot is scratch here)
            lsum += v;
        }
        __syncthreads();  // all cvinter reads done before block_sum_to reuses red
        block_sum_to(lsum, sm.red, &p.Psum2[blk]);
    }
    grid.sync();

    // ---- P5: memory pass 2 -> normalized read head + fused M_read
    {
        const float inv2 = 1.f / (p.Psum2[b * 4 + 0] + p.Psum2[b * 4 + 1]
                                + p.Psum2[b * 4 + 2] + p.Psum2[b * 4 + 3]);
        float4 acc = make_float4(0.f, 0.f, 0.f, 0.f);
        #pragma unroll 4
        for (int it = 0; it < CHUNK / 32; ++it) {
            const int n = n0 + it * 32 + rgrp;
            const float w = p.whead[bbase + n] * inv2;       // sharp_r * inv2
            const float4 m4 = ((const float4*)(p.memory + (bbase + n) * 64))[m16];
            if (m16 == 0) p.rhead[bbase + n] = w;            // final output
            acc.x += w * m4.x; acc.y += w * m4.y; acc.z += w * m4.z; acc.w += w * m4.w;
        }
        for (int off = 16; off <= 32; off <<= 1) {
            acc.x += __shfl_xor(acc.x, off); acc.y += __shfl_xor(acc.y, off);
            acc.z += __shfl_xor(acc.z, off); acc.w += __shfl_xor(acc.w, off);
        }
        const int lane = tid & 63, wid = tid >> 6;
        if (lane < 16) sm.part4[wid * 16 + lane] = acc;
        __syncthreads();
        if (tid < 16) {
            float4 t = sm.part4[tid];
            for (int w2 = 1; w2 < 8; ++w2) {
                const float4 q = sm.part4[w2 * 16 + tid];
                t.x += q.x; t.y += q.y; t.z += q.z; t.w += q.w;
            }
            atomicAdd(&p.M_read[b * 64 + tid * 4 + 0], t.x);
            atomicAdd(&p.M_read[b * 64 + tid * 4 + 1], t.y);
            atomicAdd(&p.M_read[b * 64 + tid * 4 + 2], t.z);
            atomicAdd(&p.M_read[b * 64 + tid * 4 + 3], t.w);
        }
        __syncthreads();
    }
    grid.sync();

    // ---- P6: gates split-K GEMM. 13 K-chunks x 16 j-tiles(128) = 208 tiles.
    if (blk < 208) {
        const int jt = blk & 15;
        const int ch = blk >> 4;
        const int j0 = jt * 128;
        #pragma unroll
        for (int i = 0; i < 2; ++i) {               // X: 64 b-rows x 16 float4
            const int e = i * NTHR + tid;
            const int row = e >> 4, c4 = e & 15;
            const float* xrow;
            if (ch < 4)       xrow = p.inp    + row * 256 + ch * 64;
            else if (ch == 4) xrow = p.M_read + row * 64;
            else              xrow = p.h_tm1  + row * 512 + (ch - 5) * 64;
            const float4 v = ((const float4*)xrow)[c4];
            const int kl = c4 * 4;
            sm.g.X[kl + 0][row] = v.x; sm.g.X[kl + 1][row] = v.y;
            sm.g.X[kl + 2][row] = v.z; sm.g.X[kl + 3][row] = v.w;
        }
        #pragma unroll
        for (int i = 0; i < 4; ++i) {               // W: 128 j-rows x 16 float4
            const int e = i * NTHR + tid;
            const int row = e >> 4, c4 = e & 15;
            const float* wrow;
            if (ch < 5) wrow = p.W_ih + (size_t)(j0 + row) * 320 + ch * 64;
            else        wrow = p.W_hh + (size_t)(j0 + row) * 512 + (ch - 5) * 64;
            const float4 v = ((const float4*)wrow)[c4];
            const int kl = c4 * 4;
            sm.g.W[kl + 0][row] = v.x; sm.g.W[kl + 1][row] = v.y;
            sm.g.W[kl + 2][row] = v.z; sm.g.W[kl + 3][row] = v.w;
        }
        __syncthreads();
        const int tx = tid & 31, ty = tid >> 5;     // 32 j-quads x 16 b-quads
        float acc2[4][4] = {};
        #pragma unroll
        for (int k = 0; k < 64; ++k) {
            const float4 av = *((const float4*)&sm.g.X[k][ty * 4]);
            const float4 wv = *((const float4*)&sm.g.W[k][tx * 4]);
            acc2[0][0] += av.x * wv.x; acc2[0][1] += av.x * wv.y; acc2[0][2] += av.x * wv.z; acc2[0][3] += av.x * wv.w;
            acc2[1][0] += av.y * wv.x; acc2[1][1] += av.y * wv.y; acc2[1][2] += av.y * wv.z; acc2[1][3] += av.y * wv.w;
            acc2[2][0] += av.z * wv.x; acc2[2][1] += av.z * wv.y; acc2[2][2] += av.z * wv.z; acc2[2][3] += av.z * wv.w;
            acc2[3][0] += av.w * wv.x; acc2[3][1] += av.w * wv.y; acc2[3][2] += av.w * wv.z; acc2[3][3] += av.w * wv.w;
        }
        #pragma unroll
        for (int bi = 0; bi < 4; ++bi)
            #pragma unroll
            for (int ji = 0; ji < 4; ++ji)
                atomicAdd(&p.gates[(ty * 4 + bi) * 2048 + j0 + tx * 4 + ji], acc2[bi][ji]);
        __syncthreads();
    }
    grid.sync();

    // ---- P7: LSTM elementwise (biases folded). 256 blk x 128 thr = 32768
    if (tid < 128) {
        const int idx = blk * 128 + tid;
        const int bb = idx >> 9, j = idx & 511;
        const float* gr = p.gates + bb * 2048;
        const float i_ = sigmoidf_(gr[j]        + p.b_ih[j]        + p.b_hh[j]);
        const float f_ = sigmoidf_(gr[512 + j]  + p.b_ih[512 + j]  + p.b_hh[512 + j]);
        const float g_ = tanhf(   gr[1024 + j] + p.b_ih[1024 + j] + p.b_hh[1024 + j]);
        const float o_ = sigmoidf_(gr[1536 + j] + p.b_ih[1536 + j] + p.b_hh[1536 + j]);
        const float cv = f_ * p.c_tm1[idx] + i_ * g_;
        p.c_out[idx] = cv;
        p.h_out[idx] = o_ * tanhf(cv);
    }
    grid.sync();

    // ---- P8: write-head params from h_t (blocks 0..63)
    if (blk < 64) {
        head_params(p.h_out, p.W_wk, p.b_wk, p.W_wc, p.b_wc, p.W_ws, p.b_ws,
                    p.W_w, p.b_w, 1, blk,
                    p.wk, p.wnk, p.wss, p.wbeta, p.wg, p.wgamma, p.e_buf, p.a_buf, sm.raw);
    }
    grid.sync();

    // ---- P9: memory pass 3 -> x_w (reuse nM), online pair
    {
        const float4 k4  = ((const float4*)(p.wk + b * 64))[m16];
        const float beta = p.wbeta[b], nk = p.wnk[b];
        float lm = -1e30f, ls = 0.f;
        #pragma unroll 4
        for (int it = 0; it < CHUNK / 32; ++it) {
            const int n = n0 + it * 32 + rgrp;
            const float4 m4 = ((const float4*)(p.memory + (bbase + n) * 64))[m16];
            float d = m4.x * k4.x + m4.y * k4.y + m4.z * k4.z + m4.w * k4.w;
            for (int off = 8; off >= 1; off >>= 1) d += __shfl_xor(d, off);
            if (m16 == 0) {
                float x = beta * d / (nMbuf[bbase + n] * nk);
                xbuf[bbase + n] = x;
                float mn = fmaxf(lm, x);
                ls = ls * expf(lm - mn) + expf(x - mn);
                lm = mn;
            }
        }
        block_pair_to(lm, ls, sm.red, &p.Pmax[blk], &p.Psum[blk]);
    }
    grid.sync();

    // ---- P11: write-head inter (LDS halo) -> conv -> sharpen -> whead slot
    {
        float Mx = -1e30f, Sx = 0.f;
        #pragma unroll
        for (int c2 = 0; c2 < 4; ++c2) {
            float m = p.Pmax[b * 4 + c2], s = p.Psum[b * 4 + c2];
            float mn = fmaxf(Mx, m);
            Sx = Sx * expf(Mx - mn) + s * expf(m - mn);
            Mx = mn;
        }
        const float inv = 1.f / Sx, gmax = Mx;
        const float g = p.wg[b], gamma = p.wgamma[b];
        const float s0 = p.wss[b * 3 + 0], s1 = p.wss[b * 3 + 1], s2 = p.wss[b * 3 + 2];
        #pragma unroll
        for (int j = 0; j < CHUNK / NTHR; ++j) {
            const int i = j * NTHR + tid;
            const int n = n0 + i;
            sm.cvinter[i + 2] = g * expf(xbuf[bbase + n] - gmax) * inv
                              + (1.f - g) * p.write_tm1[bbase + n];
        }
        if (tid < 2) {
            const int n = (n0 + N_ - 2 + tid) & (N_ - 1);
            sm.cvinter[tid] = g * expf(xbuf[bbase + n] - gmax) * inv
                            + (1.f - g) * p.write_tm1[bbase + n];
        }
        __syncthreads();
        float lsum = 0.f;
        #pragma unroll
        for (int j = 0; j < CHUNK / NTHR; ++j) {
            const int i = j * NTHR + tid;
            const float conv = s2 * sm.cvinter[i + 2] + s1 * sm.cvinter[i + 1]
                             + s0 * sm.cvinter[i];
            const float v = powf(fmaxf(conv, 1e-8f), gamma);
            p.whead[bbase + n0 + i] = v;      // sharp_w
            lsum += v;
        }
        __syncthreads();
        block_sum_to(lsum, sm.red, &p.Psum2[blk]);
    }
    grid.sync();

    // ---- P13: memory pass 4 -> normalized write head + M_out
    {
        const float inv2 = 1.f / (p.Psum2[b * 4 + 0] + p.Psum2[b * 4 + 1]
                                + p.Psum2[b * 4 + 2] + p.Psum2[b * 4 + 3]);
        const float4 e4 = ((const float4*)(p.e_buf + b * 64))[m16];
        const float4 a4 = ((const float4*)(p.a_buf + b * 64))[m16];
        #pragma unroll 4
        for (int it = 0; it < CHUNK / 32; ++it) {
            const int n = n0 + it * 32 + rgrp;
            const float w = p.whead[bbase + n] * inv2;   // read sharp_w (all lanes)
            const float4 m4 = ((const float4*)(p.memory + (bbase + n) * 64))[m16];
            if (m16 == 0) p.whead[bbase + n] = w;        // final output (same wave, after load)
            float4 o;
            o.x = m4.x * (1.f - w * e4.x) + w * a4.x;
            o.y = m4.y * (1.f - w * e4.y) + w * a4.y;
            o.z = m4.z * (1.f - w * e4.z) + w * a4.z;
            o.w = m4.w * (1.f - w * e4.w) + w * a4.w;
            ((float4*)(p.Mout + (bbase + n) * 64))[m16] = o;
        }
    }
}

// ---------------------------------------------------------------------------
extern "C" void kernel_launch(void* const* d_in, const int* in_sizes, int n_in,
                              void* d_out, int out_size, void* d_ws, size_t ws_size,
                              hipStream_t stream)
{
    Args p;
    p.inp       = (const float*)d_in[0];
    p.h_tm1     = (const float*)d_in[1];
    p.c_tm1     = (const float*)d_in[2];
    p.read_tm1  = (const float*)d_in[3];
    p.write_tm1 = (const float*)d_in[4];
    p.memory    = (const float*)d_in[5];
    p.W_ih = (const float*)d_in[6];  p.b_ih = (const float*)d_in[7];
    p.W_hh = (const float*)d_in[8];  p.b_hh = (const float*)d_in[9];
    p.W_rk = (const float*)d_in[10]; p.b_rk = (const float*)d_in[11];
    p.W_wk = (const float*)d_in[12]; p.b_wk = (const float*)d_in[13];
    p.W_rc = (const float*)d_in[14]; p.b_rc = (const float*)d_in[15];
    p.W_wc = (const float*)d_in[16]; p.b_wc = (const float*)d_in[17];
    p.W_rs = (const float*)d_in[18]; p.b_rs = (const float*)d_in[19];
    p.W_ws = (const float*)d_in[20]; p.b_ws = (const float*)d_in[21];
    p.W_w  = (const float*)d_in[22]; p.b_w  = (const float*)d_in[23];

    float* out = (float*)d_out;
    p.h_out = out;                          // B*H
    p.c_out = out + 32768;                  // B*H
    p.rhead = out + 65536;                  // B*N
    p.whead = out + 65536 + 1048576;        // B*N (used as sharp scratch pre-final)
    p.Mout  = out + 65536 + 2 * 1048576;    // B*N*M (first 2*B*N floats = nM | x scratch)

    float* ws = (float*)d_ws;
    p.gates  = ws;              // 131072
    p.rk     = ws + 131072;     // 4096
    p.wk     = ws + 135168;     // 4096
    p.M_read = ws + 139264;     // 4096
    p.e_buf  = ws + 143360;     // 4096
    p.a_buf  = ws + 147456;     // 4096
    p.rs     = ws + 151552;     // 192
    p.wss    = ws + 151744;     // 192
    p.rbeta  = ws + 151936;
    p.rg     = ws + 152000;
    p.rgamma = ws + 152064;
    p.rnk    = ws + 152128;
    p.wbeta  = ws + 152192;
    p.wg     = ws + 152256;
    p.wgamma = ws + 152320;
    p.wnk    = ws + 152384;
    p.Pmax   = ws + 152448;     // 256
    p.Psum   = ws + 152704;     // 256
    p.Psum2  = ws + 152960;     // 256

    void* kargs[] = { (void*)&p };
    hipLaunchCooperativeKernel((const void*)ntm_mega, dim3(NBLK), dim3(NTHR),
                               kargs, 0, stream);
}

// Round 3
// 1031.313 us; speedup vs baseline: 1.1767x; 1.1767x over previous
//
#include <hip/hip_runtime.h>
#include <hip/hip_cooperative_groups.h>
#include <math.h>

namespace cg = cooperative_groups;

#define B_  64
#define D_  256
#define H_  512
#define N_  16384
#define M_  64
#define EPS_ 1e-4f

#define NBLK 256
#define NTHR 1024
#define NWAVE (NTHR / 64)      // 16 waves/block -> 16 waves/CU
#define CHUNK (N_ / 4)         // rows per block in streaming phases (4 blocks/batch)

struct Args {
  const float *inp, *h_tm1, *c_tm1, *read_tm1, *write_tm1, *memory;
  const float *W_ih, *b_ih, *W_hh, *b_hh;
  const float *W_rk, *b_rk, *W_wk, *b_wk;
  const float *W_rc, *b_rc, *W_wc, *b_wc;
  const float *W_rs, *b_rs, *W_ws, *b_ws;
  const float *W_w, *b_w;
  float *h_out, *c_out, *rhead, *whead, *Mout;
  float *gates, *rk, *wk, *M_read, *e_buf, *a_buf, *rs, *wss;
  float *rbeta, *rg, *rgamma, *rnk, *wbeta, *wg, *wgamma, *wnk;
  float *Pmax, *Psum, *Psum2;
};

union Smem {
  float raw[256];                          // head_params GEMV rows
  float red[32];                           // block reduce scratch (16 waves, m+s)
  float4 part4[256];                       // M_read reduce (16 waves x 16)
  float cvinter[CHUNK + 2];                // inter chunk + 2-left halo for conv
  // gates GEMM staging: X[k][b] (64x64, pad 68), W[k][j] (64x128, pad 132).
  struct { float X[64][68]; float W[64][132]; } g;   // 51.2 KB
};

__device__ __forceinline__ float sigmoidf_(float x) { return 1.0f / (1.0f + expf(-x)); }

// block-wide sum of v -> *out written by tid 0 (red = 32-float LDS scratch)
__device__ __forceinline__ void block_sum_to(float v, float* red, float* out) {
    for (int off = 32; off >= 1; off >>= 1) v += __shfl_xor(v, off);
    const int wid = threadIdx.x >> 6;
    if ((threadIdx.x & 63) == 0) red[wid] = v;
    __syncthreads();
    if (threadIdx.x == 0) {
        float s = red[0];
        #pragma unroll
        for (int i = 1; i < NWAVE; ++i) s += red[i];
        *out = s;
    }
    __syncthreads();
}

// block-wide online-softmax pair combine; (m,s) neutral element = (-1e30, 0)
__device__ __forceinline__ void block_pair_to(float m, float s, float* red,
                                              float* outm, float* outs) {
    for (int off = 32; off >= 1; off >>= 1) {
        float m2 = __shfl_xor(m, off), s2 = __shfl_xor(s, off);
        float mn = fmaxf(m, m2);
        s = s * expf(m - mn) + s2 * expf(m2 - mn);
        m = mn;
    }
    const int wid = threadIdx.x >> 6;
    if ((threadIdx.x & 63) == 0) { red[wid] = m; red[NWAVE + wid] = s; }
    __syncthreads();
    if (threadIdx.x == 0) {
        float M = red[0], S = red[NWAVE];
        for (int i = 1; i < NWAVE; ++i) {
            float mn = fmaxf(M, red[i]);
            S = S * expf(M - mn) + red[NWAVE + i] * expf(red[i] - mn);
            M = mn;
        }
        *outm = M; *outs = S;
    }
    __syncthreads();
}

// wave-per-row GEMV head params (16 waves), block handles batch b
__device__ void head_params(const float* h,
    const float* Wk, const float* bk, const float* Wc, const float* bc,
    const float* Ws, const float* bs, const float* Ww, const float* bw,
    int with_w, int b,
    float* k_out, float* nk_out, float* s_out,
    float* beta_out, float* g_out, float* gamma_out,
    float* e_out, float* a_out, float* raw)
{
    const int tid = threadIdx.x;
    const int lane = tid & 63;
    const int wid = tid >> 6;
    float h8[8];
    #pragma unroll
    for (int j = 0; j < 8; ++j) h8[j] = h[b * H_ + lane + 64 * j];
    const int count = with_w ? 198 : 70;
    for (int r = wid; r < count; r += NWAVE) {
        const float* wrow; float bias;
        if (r < 64)      { wrow = Wk + r * H_;          bias = bk[r]; }
        else if (r < 67) { wrow = Wc + (r - 64) * H_;   bias = bc[r - 64]; }
        else if (r < 70) { wrow = Ws + (r - 67) * H_;   bias = bs[r - 67]; }
        else             { wrow = Ww + (r - 70) * H_;   bias = bw[r - 70]; }
        float acc = 0.f;
        #pragma unroll
        for (int j = 0; j < 8; ++j) acc += wrow[lane + 64 * j] * h8[j];
        for (int off = 32; off >= 1; off >>= 1) acc += __shfl_xor(acc, off);
        if (lane == 0) raw[r] = acc + bias;
    }
    __syncthreads();
    if (tid < 64) {
        float kv = tanhf(raw[tid]);
        k_out[b * 64 + tid] = kv;
        float sq = kv * kv;
        for (int off = 32; off >= 1; off >>= 1) sq += __shfl_xor(sq, off);
        if (tid == 0) nk_out[b] = sqrtf(sq) + EPS_;
    } else if (tid == 64) {
        beta_out[b]  = fmaxf(raw[64], 0.f) + EPS_;
        g_out[b]     = sigmoidf_(raw[65]);
        gamma_out[b] = fmaxf(raw[66], 0.f) + 1.f + EPS_;
    } else if (tid == 65) {
        float s0 = raw[67], s1 = raw[68], s2 = raw[69];
        float mx = fmaxf(s0, fmaxf(s1, s2));
        float e0 = expf(s0 - mx), e1 = expf(s1 - mx), e2 = expf(s2 - mx);
        float inv = 1.f / (e0 + e1 + e2);
        s_out[b * 3 + 0] = e0 * inv;
        s_out[b * 3 + 1] = e1 * inv;
        s_out[b * 3 + 2] = e2 * inv;
    }
    if (with_w && tid >= 128 && tid < 192) {
        int m = tid - 128;
        e_out[b * 64 + m] = sigmoidf_(raw[70 + m]);
        a_out[b * 64 + m] = raw[134 + m];
    }
    __syncthreads();
}

__global__ __launch_bounds__(NTHR) void ntm_mega(Args p)
{
    cg::grid_group grid = cg::this_grid();
    __shared__ Smem sm;

    const int blk  = blockIdx.x;
    const int tid  = threadIdx.x;
    const int m16  = tid & 15;
    const int rgrp = tid >> 4;            // 0..63 (row group in streaming phases)
    const int b    = blk >> 2;            // batch for streaming phases
    const int cc   = blk & 3;             // chunk 0..3
    const int n0   = cc * CHUNK;
    const size_t bbase = (size_t)b * N_;

    float* xbuf  = p.Mout + (size_t)B_ * N_;   // scratch, dead before P13
    float* nMbuf = p.Mout;                     // scratch, dead before P13

    // ---- P0: read-head params (blocks 0..63) | zero gates + M_read (rest)
    if (blk < 64) {
        head_params(p.h_tm1, p.W_rk, p.b_rk, p.W_rc, p.b_rc, p.W_rs, p.b_rs,
                    nullptr, nullptr, 0, blk,
                    p.rk, p.rnk, p.rs, p.rbeta, p.rg, p.rgamma, nullptr, nullptr, sm.raw);
    } else {
        for (int i = (blk - 64) * NTHR + tid; i < B_ * 4 * H_; i += 192 * NTHR)
            p.gates[i] = 0.f;
        if (blk == 64)
            for (int i = tid; i < B_ * M_; i += NTHR) p.M_read[i] = 0.f;
    }
    grid.sync();

    // ---- P1: memory pass 1 -> x (content arg), nM, online (max,sum) pair
    {
        const float4 k4  = ((const float4*)(p.rk + b * 64))[m16];
        const float beta = p.rbeta[b], nk = p.rnk[b];
        float lm = -1e30f, ls = 0.f;
        #pragma unroll 4
        for (int it = 0; it < CHUNK / 64; ++it) {
            const int n = n0 + it * 64 + rgrp;
            const float4 m4 = ((const float4*)(p.memory + (bbase + n) * 64))[m16];
            float d  = m4.x * k4.x + m4.y * k4.y + m4.z * k4.z + m4.w * k4.w;
            float sq = m4.x * m4.x + m4.y * m4.y + m4.z * m4.z + m4.w * m4.w;
            for (int off = 8; off >= 1; off >>= 1) {
                d += __shfl_xor(d, off); sq += __shfl_xor(sq, off);
            }
            if (m16 == 0) {
                float nMv = sqrtf(sq) + EPS_;
                float x = beta * d / (nMv * nk);
                xbuf[bbase + n]  = x;
                nMbuf[bbase + n] = nMv;
                float mn = fmaxf(lm, x);
                ls = ls * expf(lm - mn) + expf(x - mn);
                lm = mn;
            }
        }
        block_pair_to(lm, ls, sm.red, &p.Pmax[blk], &p.Psum[blk]);
    }
    grid.sync();

    // ---- P3: inter (LDS w/ halo) -> conv -> sharpen -> sharp in whead slot
    {
        float Mx = -1e30f, Sx = 0.f;
        #pragma unroll
        for (int c2 = 0; c2 < 4; ++c2) {
            float m = p.Pmax[b * 4 + c2], s = p.Psum[b * 4 + c2];
            float mn = fmaxf(Mx, m);
            Sx = Sx * expf(Mx - mn) + s * expf(m - mn);
            Mx = mn;
        }
        const float inv = 1.f / Sx, gmax = Mx;
        const float g = p.rg[b], gamma = p.rgamma[b];
        const float s0 = p.rs[b * 3 + 0], s1 = p.rs[b * 3 + 1], s2 = p.rs[b * 3 + 2];
        #pragma unroll
        for (int j = 0; j < CHUNK / NTHR; ++j) {
            const int i = j * NTHR + tid;
            const int n = n0 + i;
            sm.cvinter[i + 2] = g * expf(xbuf[bbase + n] - gmax) * inv
                              + (1.f - g) * p.read_tm1[bbase + n];
        }
        if (tid < 2) {
            const int n = (n0 + N_ - 2 + tid) & (N_ - 1);
            sm.cvinter[tid] = g * expf(xbuf[bbase + n] - gmax) * inv
                            + (1.f - g) * p.read_tm1[bbase + n];
        }
        __syncthreads();
        float lsum = 0.f;
        #pragma unroll
        for (int j = 0; j < CHUNK / NTHR; ++j) {
            const int i = j * NTHR + tid;
            const float conv = s2 * sm.cvinter[i + 2] + s1 * sm.cvinter[i + 1]
                             + s0 * sm.cvinter[i];
            const float v = powf(fmaxf(conv, 1e-8f), gamma);
            p.whead[bbase + n0 + i] = v;      // sharp_r (whead slot is scratch here)
            lsum += v;
        }
        __syncthreads();  // all cvinter reads done before block_sum_to reuses red
        block_sum_to(lsum, sm.red, &p.Psum2[blk]);
    }
    grid.sync();

    // ---- P5: memory pass 2 -> normalized read head + fused M_read
    {
        const float inv2 = 1.f / (p.Psum2[b * 4 + 0] + p.Psum2[b * 4 + 1]
                                + p.Psum2[b * 4 + 2] + p.Psum2[b * 4 + 3]);
        float4 acc = make_float4(0.f, 0.f, 0.f, 0.f);
        #pragma unroll 4
        for (int it = 0; it < CHUNK / 64; ++it) {
            const int n = n0 + it * 64 + rgrp;
            const float w = p.whead[bbase + n] * inv2;       // sharp_r * inv2
            const float4 m4 = ((const float4*)(p.memory + (bbase + n) * 64))[m16];
            if (m16 == 0) p.rhead[bbase + n] = w;            // final output
            acc.x += w * m4.x; acc.y += w * m4.y; acc.z += w * m4.z; acc.w += w * m4.w;
        }
        for (int off = 16; off <= 32; off <<= 1) {
            acc.x += __shfl_xor(acc.x, off); acc.y += __shfl_xor(acc.y, off);
            acc.z += __shfl_xor(acc.z, off); acc.w += __shfl_xor(acc.w, off);
        }
        const int lane = tid & 63, wid = tid >> 6;
        if (lane < 16) sm.part4[wid * 16 + lane] = acc;
        __syncthreads();
        if (tid < 16) {
            float4 t = sm.part4[tid];
            for (int w2 = 1; w2 < NWAVE; ++w2) {
                const float4 q = sm.part4[w2 * 16 + tid];
                t.x += q.x; t.y += q.y; t.z += q.z; t.w += q.w;
            }
            atomicAdd(&p.M_read[b * 64 + tid * 4 + 0], t.x);
            atomicAdd(&p.M_read[b * 64 + tid * 4 + 1], t.y);
            atomicAdd(&p.M_read[b * 64 + tid * 4 + 2], t.z);
            atomicAdd(&p.M_read[b * 64 + tid * 4 + 3], t.w);
        }
        __syncthreads();
    }
    grid.sync();

    // ---- P6: gates split-K GEMM. 13 K-chunks x 16 j-tiles(128) = 208 tiles.
    if (blk < 208) {
        const int jt = blk & 15;
        const int ch = blk >> 4;
        const int j0 = jt * 128;
        {                                            // X: 64 b-rows x 16 float4
            const int row = tid >> 4, c4 = tid & 15;
            const float* xrow;
            if (ch < 4)       xrow = p.inp    + row * 256 + ch * 64;
            else if (ch == 4) xrow = p.M_read + row * 64;
            else              xrow = p.h_tm1  + row * 512 + (ch - 5) * 64;
            const float4 v = ((const float4*)xrow)[c4];
            const int kl = c4 * 4;
            sm.g.X[kl + 0][row] = v.x; sm.g.X[kl + 1][row] = v.y;
            sm.g.X[kl + 2][row] = v.z; sm.g.X[kl + 3][row] = v.w;
        }
        #pragma unroll
        for (int i = 0; i < 2; ++i) {                // W: 128 j-rows x 16 float4
            const int e = i * NTHR + tid;
            const int row = e >> 4, c4 = e & 15;
            const float* wrow;
            if (ch < 5) wrow = p.W_ih + (size_t)(j0 + row) * 320 + ch * 64;
            else        wrow = p.W_hh + (size_t)(j0 + row) * 512 + (ch - 5) * 64;
            const float4 v = ((const float4*)wrow)[c4];
            const int kl = c4 * 4;
            sm.g.W[kl + 0][row] = v.x; sm.g.W[kl + 1][row] = v.y;
            sm.g.W[kl + 2][row] = v.z; sm.g.W[kl + 3][row] = v.w;
        }
        __syncthreads();
        const int tx = tid & 31, ty = tid >> 5;      // 32 j-quads x 32 b-pairs
        float acc2[2][4] = {};
        #pragma unroll
        for (int k = 0; k < 64; ++k) {
            const float2 av = *((const float2*)&sm.g.X[k][ty * 2]);
            const float4 wv = *((const float4*)&sm.g.W[k][tx * 4]);
            acc2[0][0] += av.x * wv.x; acc2[0][1] += av.x * wv.y; acc2[0][2] += av.x * wv.z; acc2[0][3] += av.x * wv.w;
            acc2[1][0] += av.y * wv.x; acc2[1][1] += av.y * wv.y; acc2[1][2] += av.y * wv.z; acc2[1][3] += av.y * wv.w;
        }
        #pragma unroll
        for (int bi = 0; bi < 2; ++bi)
            #pragma unroll
            for (int ji = 0; ji < 4; ++ji)
                atomicAdd(&p.gates[(ty * 2 + bi) * 2048 + j0 + tx * 4 + ji], acc2[bi][ji]);
        __syncthreads();
    }
    grid.sync();

    // ---- P7: LSTM elementwise (biases folded). 256 blk x 128 thr = 32768
    if (tid < 128) {
        const int idx = blk * 128 + tid;
        const int bb = idx >> 9, j = idx & 511;
        const float* gr = p.gates + bb * 2048;
        const float i_ = sigmoidf_(gr[j]        + p.b_ih[j]        + p.b_hh[j]);
        const float f_ = sigmoidf_(gr[512 + j]  + p.b_ih[512 + j]  + p.b_hh[512 + j]);
        const float g_ = tanhf(   gr[1024 + j] + p.b_ih[1024 + j] + p.b_hh[1024 + j]);
        const float o_ = sigmoidf_(gr[1536 + j] + p.b_ih[1536 + j] + p.b_hh[1536 + j]);
        const float cv = f_ * p.c_tm1[idx] + i_ * g_;
        p.c_out[idx] = cv;
        p.h_out[idx] = o_ * tanhf(cv);
    }
    grid.sync();

    // ---- P8: write-head params from h_t (blocks 0..63)
    if (blk < 64) {
        head_params(p.h_out, p.W_wk, p.b_wk, p.W_wc, p.b_wc, p.W_ws, p.b_ws,
                    p.W_w, p.b_w, 1, blk,
                    p.wk, p.wnk, p.wss, p.wbeta, p.wg, p.wgamma, p.e_buf, p.a_buf, sm.raw);
    }
    grid.sync();

    // ---- P9: memory pass 3 -> x_w (reuse nM), online pair
    {
        const float4 k4  = ((const float4*)(p.wk + b * 64))[m16];
        const float beta = p.wbeta[b], nk = p.wnk[b];
        float lm = -1e30f, ls = 0.f;
        #pragma unroll 4
        for (int it = 0; it < CHUNK / 64; ++it) {
            const int n = n0 + it * 64 + rgrp;
            const float4 m4 = ((const float4*)(p.memory + (bbase + n) * 64))[m16];
            float d = m4.x * k4.x + m4.y * k4.y + m4.z * k4.z + m4.w * k4.w;
            for (int off = 8; off >= 1; off >>= 1) d += __shfl_xor(d, off);
            if (m16 == 0) {
                float x = beta * d / (nMbuf[bbase + n] * nk);
                xbuf[bbase + n] = x;
                float mn = fmaxf(lm, x);
                ls = ls * expf(lm - mn) + expf(x - mn);
                lm = mn;
            }
        }
        block_pair_to(lm, ls, sm.red, &p.Pmax[blk], &p.Psum[blk]);
    }
    grid.sync();

    // ---- P11: write-head inter (LDS halo) -> conv -> sharpen -> whead slot
    {
        float Mx = -1e30f, Sx = 0.f;
        #pragma unroll
        for (int c2 = 0; c2 < 4; ++c2) {
            float m = p.Pmax[b * 4 + c2], s = p.Psum[b * 4 + c2];
            float mn = fmaxf(Mx, m);
            Sx = Sx * expf(Mx - mn) + s * expf(m - mn);
            Mx = mn;
        }
        const float inv = 1.f / Sx, gmax = Mx;
        const float g = p.wg[b], gamma = p.wgamma[b];
        const float s0 = p.wss[b * 3 + 0], s1 = p.wss[b * 3 + 1], s2 = p.wss[b * 3 + 2];
        #pragma unroll
        for (int j = 0; j < CHUNK / NTHR; ++j) {
            const int i = j * NTHR + tid;
            const int n = n0 + i;
            sm.cvinter[i + 2] = g * expf(xbuf[bbase + n] - gmax) * inv
                              + (1.f - g) * p.write_tm1[bbase + n];
        }
        if (tid < 2) {
            const int n = (n0 + N_ - 2 + tid) & (N_ - 1);
            sm.cvinter[tid] = g * expf(xbuf[bbase + n] - gmax) * inv
                            + (1.f - g) * p.write_tm1[bbase + n];
        }
        __syncthreads();
        float lsum = 0.f;
        #pragma unroll
        for (int j = 0; j < CHUNK / NTHR; ++j) {
            const int i = j * NTHR + tid;
            const float conv = s2 * sm.cvinter[i + 2] + s1 * sm.cvinter[i + 1]
                             + s0 * sm.cvinter[i];
            const float v = powf(fmaxf(conv, 1e-8f), gamma);
            p.whead[bbase + n0 + i] = v;      // sharp_w
            lsum += v;
        }
        __syncthreads();
        block_sum_to(lsum, sm.red, &p.Psum2[blk]);
    }
    grid.sync();

    // ---- P13: memory pass 4 -> normalized write head + M_out
    {
        const float inv2 = 1.f / (p.Psum2[b * 4 + 0] + p.Psum2[b * 4 + 1]
                                + p.Psum2[b * 4 + 2] + p.Psum2[b * 4 + 3]);
        const float4 e4 = ((const float4*)(p.e_buf + b * 64))[m16];
        const float4 a4 = ((const float4*)(p.a_buf + b * 64))[m16];
        #pragma unroll 4
        for (int it = 0; it < CHUNK / 64; ++it) {
            const int n = n0 + it * 64 + rgrp;
            const float w = p.whead[bbase + n] * inv2;   // read sharp_w (all lanes)
            const float4 m4 = ((const float4*)(p.memory + (bbase + n) * 64))[m16];
            if (m16 == 0) p.whead[bbase + n] = w;        // final output (same wave, after load)
            float4 o;
            o.x = m4.x * (1.f - w * e4.x) + w * a4.x;
            o.y = m4.y * (1.f - w * e4.y) + w * a4.y;
            o.z = m4.z * (1.f - w * e4.z) + w * a4.z;
            o.w = m4.w * (1.f - w * e4.w) + w * a4.w;
            ((float4*)(p.Mout + (bbase + n) * 64))[m16] = o;
        }
    }
}

// ---------------------------------------------------------------------------
extern "C" void kernel_launch(void* const* d_in, const int* in_sizes, int n_in,
                              void* d_out, int out_size, void* d_ws, size_t ws_size,
                              hipStream_t stream)
{
    Args p;
    p.inp       = (const float*)d_in[0];
    p.h_tm1     = (const float*)d_in[1];
    p.c_tm1     = (const float*)d_in[2];
    p.read_tm1  = (const float*)d_in[3];
    p.write_tm1 = (const float*)d_in[4];
    p.memory    = (const float*)d_in[5];
    p.W_ih = (const float*)d_in[6];  p.b_ih = (const float*)d_in[7];
    p.W_hh = (const float*)d_in[8];  p.b_hh = (const float*)d_in[9];
    p.W_rk = (const float*)d_in[10]; p.b_rk = (const float*)d_in[11];
    p.W_wk = (const float*)d_in[12]; p.b_wk = (const float*)d_in[13];
    p.W_rc = (const float*)d_in[14]; p.b_rc = (const float*)d_in[15];
    p.W_wc = (const float*)d_in[16]; p.b_wc = (const float*)d_in[17];
    p.W_rs = (const float*)d_in[18]; p.b_rs = (const float*)d_in[19];
    p.W_ws = (const float*)d_in[20]; p.b_ws = (const float*)d_in[21];
    p.W_w  = (const float*)d_in[22]; p.b_w  = (const float*)d_in[23];

    float* out = (float*)d_out;
    p.h_out = out;                          // B*H
    p.c_out = out + 32768;                  // B*H
    p.rhead = out + 65536;                  // B*N
    p.whead = out + 65536 + 1048576;        // B*N (used as sharp scratch pre-final)
    p.Mout  = out + 65536 + 2 * 1048576;    // B*N*M (first 2*B*N floats = nM | x scratch)

    float* ws = (float*)d_ws;
    p.gates  = ws;              // 131072
    p.rk     = ws + 131072;     // 4096
    p.wk     = ws + 135168;     // 4096
    p.M_read = ws + 139264;     // 4096
    p.e_buf  = ws + 143360;     // 4096
    p.a_buf  = ws + 147456;     // 4096
    p.rs     = ws + 151552;     // 192
    p.wss    = ws + 151744;     // 192
    p.rbeta  = ws + 151936;
    p.rg     = ws + 152000;
    p.rgamma = ws + 152064;
    p.rnk    = ws + 152128;
    p.wbeta  = ws + 152192;
    p.wg     = ws + 152256;
    p.wgamma = ws + 152320;
    p.wnk    = ws + 152384;
    p.Pmax   = ws + 152448;     // 256
    p.Psum   = ws + 152704;     // 256
    p.Psum2  = ws + 152960;     // 256

    void* kargs[] = { (void*)&p };
    hipLaunchCooperativeKernel((const void*)ntm_mega, dim3(NBLK), dim3(NTHR),
                               kargs, 0, stream);
}

// Round 5
// 817.657 us; speedup vs baseline: 1.4841x; 1.2613x over previous
//
#include <hip/hip_runtime.h>
#include <math.h>

#define B_  64
#define D_  256
#define H_  512
#define N_  16384
#define M_  64
#define S_  3
#define EPS_ 1e-4f

__device__ __forceinline__ float sigmoidf_(float x) { return 1.0f / (1.0f + expf(-x)); }

// ---------------------------------------------------------------------------
// K1/K8: head params.  One block per batch, 4 waves. Wave-per-row GEMV.
// (known-good from 785us baseline)
// ---------------------------------------------------------------------------
template <bool WITH_W>
__global__ __launch_bounds__(256) void head_params_kernel(
    const float* __restrict__ h,
    const float* __restrict__ Wk, const float* __restrict__ bk,
    const float* __restrict__ Wc, const float* __restrict__ bc,
    const float* __restrict__ Ws, const float* __restrict__ bs,
    const float* __restrict__ Ww, const float* __restrict__ bw,
    float* __restrict__ k_out, float* __restrict__ nk_out,
    float* __restrict__ s_out,
    float* __restrict__ beta_out, float* __restrict__ g_out, float* __restrict__ gamma_out,
    float* __restrict__ e_out, float* __restrict__ a_out)
{
    const int b = blockIdx.x;
    const int tid = threadIdx.x;
    const int lane = tid & 63;
    const int wid = tid >> 6;
    __shared__ float raw[198];

    float h8[8];
    #pragma unroll
    for (int j = 0; j < 8; ++j) h8[j] = h[b * H_ + lane + 64 * j];

    const int count = WITH_W ? 198 : 70;
    for (int r = wid; r < count; r += 4) {
        const float* wrow;
        float bias;
        if (r < 64)       { wrow = Wk + r * H_;        bias = bk[r]; }
        else if (r < 67)  { wrow = Wc + (r - 64) * H_; bias = bc[r - 64]; }
        else if (r < 70)  { wrow = Ws + (r - 67) * H_; bias = bs[r - 67]; }
        else              { wrow = Ww + (r - 70) * H_; bias = bw[r - 70]; }
        float acc = 0.f;
        #pragma unroll
        for (int j = 0; j < 8; ++j) acc += wrow[lane + 64 * j] * h8[j];
        for (int off = 32; off >= 1; off >>= 1) acc += __shfl_xor(acc, off);
        if (lane == 0) raw[r] = acc + bias;
    }
    __syncthreads();

    if (tid < 64) {
        float kv = tanhf(raw[tid]);
        k_out[b * 64 + tid] = kv;
        float sq = kv * kv;
        for (int off = 32; off >= 1; off >>= 1) sq += __shfl_xor(sq, off);
        if (tid == 0) nk_out[b] = sqrtf(sq) + EPS_;
    } else if (tid == 64) {
        float c0 = raw[64], c1 = raw[65], c2 = raw[66];
        beta_out[b]  = fmaxf(c0, 0.f) + EPS_;
        g_out[b]     = sigmoidf_(c1);
        gamma_out[b] = fmaxf(c2, 0.f) + 1.f + EPS_;
    } else if (tid == 65) {
        float s0 = raw[67], s1 = raw[68], s2 = raw[69];
        float mx = fmaxf(s0, fmaxf(s1, s2));
        float e0 = expf(s0 - mx), e1 = expf(s1 - mx), e2 = expf(s2 - mx);
        float inv = 1.f / (e0 + e1 + e2);
        s_out[b * 3 + 0] = e0 * inv;
        s_out[b * 3 + 1] = e1 * inv;
        s_out[b * 3 + 2] = e2 * inv;
    }
    if (WITH_W && tid >= 128 && tid < 192) {
        int m = tid - 128;
        e_out[b * 64 + m] = sigmoidf_(raw[70 + m]);
        a_out[b * 64 + m] = raw[134 + m];
    }
}

// ---------------------------------------------------------------------------
// K2/K9: score pass.  x[b,n] = beta * (k.mem_row) / (nM * nk), fused.
// MODE 0: also compute+store nM.  MODE 1: load stored nM.
// 16 lanes per row (float4), 64 rows/block, grid = B*256 (full occupancy).
// ---------------------------------------------------------------------------
template <int MODE>
__global__ __launch_bounds__(256) void score_kernel(
    const float* __restrict__ memory,
    const float* __restrict__ k,
    const float* __restrict__ beta_a,
    const float* __restrict__ nk_a,
    float* __restrict__ xout,
    float* __restrict__ nMbuf)
{
    const int tid = threadIdx.x;
    const int lane = tid & 63;
    const int wid = tid >> 6;
    const int grp = lane >> 4;
    const int m16 = lane & 15;
    const int b = blockIdx.x >> 8;
    const int nbase = (blockIdx.x & 255) * 64;
    const float4 k4 = ((const float4*)(k + b * 64))[m16];
    const float beta = beta_a[b], nk = nk_a[b];
    const int slot = wid * 4 + grp;
    const size_t bbase = (size_t)b * N_;
    #pragma unroll
    for (int it = 0; it < 4; ++it) {
        const int n = nbase + it * 16 + slot;
        const float4 m4 = ((const float4*)(memory + (bbase + n) * 64))[m16];
        float d  = m4.x * k4.x + m4.y * k4.y + m4.z * k4.z + m4.w * k4.w;
        float sq = 0.f;
        if (MODE == 0) sq = m4.x * m4.x + m4.y * m4.y + m4.z * m4.z + m4.w * m4.w;
        for (int off = 8; off >= 1; off >>= 1) {
            d += __shfl_xor(d, off);
            if (MODE == 0) sq += __shfl_xor(sq, off);
        }
        if (m16 == 0) {
            float nMv;
            if (MODE == 0) {
                nMv = sqrtf(sq) + EPS_;
                nMbuf[bbase + n] = nMv;
            } else {
                nMv = nMbuf[bbase + n];
            }
            xout[bbase + n] = beta * d / (nMv * nk);
        }
    }
}

// ---------------------------------------------------------------------------
// K3/K10: per-batch softmax stats over x.  One block (1024thr) per batch.
// ---------------------------------------------------------------------------
__global__ __launch_bounds__(1024) void softmax_stats_kernel(
    const float* __restrict__ x,
    float* __restrict__ gmax_a, float* __restrict__ ginv_a)
{
    __shared__ float red[17];
    const int tid = threadIdx.x;
    const int b = blockIdx.x;
    const size_t base = (size_t)b * N_;
    const int wid = tid >> 6;

    float lx[16];
    float lmax = -1e30f;
    #pragma unroll
    for (int t = 0; t < 16; ++t) {
        lx[t] = x[base + t * 1024 + tid];
        lmax = fmaxf(lmax, lx[t]);
    }
    for (int off = 32; off >= 1; off >>= 1) lmax = fmaxf(lmax, __shfl_xor(lmax, off));
    if ((tid & 63) == 0) red[wid] = lmax;
    __syncthreads();
    if (tid == 0) {
        float v = red[0];
        for (int i = 1; i < 16; ++i) v = fmaxf(v, red[i]);
        red[16] = v;
    }
    __syncthreads();
    const float gmax = red[16];
    __syncthreads();   // everyone read gmax before red reuse

    float lsum = 0.f;
    #pragma unroll
    for (int t = 0; t < 16; ++t) lsum += expf(lx[t] - gmax);
    for (int off = 32; off >= 1; off >>= 1) lsum += __shfl_xor(lsum, off);
    if ((tid & 63) == 0) red[wid] = lsum;
    __syncthreads();
    if (tid == 0) {
        float v = 0.f;
        for (int i = 0; i < 16; ++i) v += red[i];
        gmax_a[b] = gmax;
        ginv_a[b] = 1.f / v;
    }
}

// ---------------------------------------------------------------------------
// K4/K11: elementwise inter->conv->sharpen.  Recomputes neighbor inter values
// inline (L1/L2 hits) -- no LDS staging, no halo sync.  Grid = B*64 x 256thr.
// Writes sharp; atomicAdd per-block partial of sum(sharp) into ssum[b].
// ---------------------------------------------------------------------------
__global__ __launch_bounds__(256) void conv_sharp_kernel(
    const float* __restrict__ x,
    const float* __restrict__ w_tm1,
    const float* __restrict__ gmax_a, const float* __restrict__ ginv_a,
    const float* __restrict__ g_a, const float* __restrict__ gamma_a,
    const float* __restrict__ s_a,
    float* __restrict__ sharp, float* __restrict__ ssum)
{
    __shared__ float red[4];
    const int tid = threadIdx.x;
    const int b = blockIdx.x >> 6;
    const int n = (blockIdx.x & 63) * 256 + tid;
    const size_t base = (size_t)b * N_;
    const float gmax = gmax_a[b], ginv = ginv_a[b];
    const float g = g_a[b], gamma = gamma_a[b];
    const float s0 = s_a[b * 3 + 0], s1 = s_a[b * 3 + 1], s2 = s_a[b * 3 + 2];

    const int n1 = (n + N_ - 1) & (N_ - 1);
    const int n2 = (n + N_ - 2) & (N_ - 1);
    const float i0 = g * expf(x[base + n]  - gmax) * ginv + (1.f - g) * w_tm1[base + n];
    const float i1 = g * expf(x[base + n1] - gmax) * ginv + (1.f - g) * w_tm1[base + n1];
    const float i2 = g * expf(x[base + n2] - gmax) * ginv + (1.f - g) * w_tm1[base + n2];
    const float conv = s2 * i0 + s1 * i1 + s0 * i2;
    const float v = powf(fmaxf(conv, 1e-8f), gamma);
    sharp[base + n] = v;

    float lsum = v;
    for (int off = 32; off >= 1; off >>= 1) lsum += __shfl_xor(lsum, off);
    if ((tid & 63) == 0) red[tid >> 6] = lsum;
    __syncthreads();
    if (tid == 0) atomicAdd(&ssum[b], red[0] + red[1] + red[2] + red[3]);
}

// ---------------------------------------------------------------------------
// K5: normalized read head + fused M_read.  Grid = B*64 (256 n per block).
// M_read pre-zeroed.  rhead[n] = sharp[n]/ssum written here (final output).
// ---------------------------------------------------------------------------
__global__ __launch_bounds__(256) void mread_norm_kernel(
    const float* __restrict__ memory,
    const float* __restrict__ sharp,
    const float* __restrict__ ssum,
    float* __restrict__ rhead,
    float* __restrict__ M_read)
{
    const int tid = threadIdx.x;
    const int lane = tid & 63;
    const int wid = tid >> 6;
    const int grp = lane >> 4;
    const int m16 = lane & 15;
    const int b = blockIdx.x >> 6;
    const int nbase = (blockIdx.x & 63) * 256;
    const int slot = wid * 4 + grp;
    const size_t bbase = (size_t)b * N_;
    const float inv2 = 1.f / ssum[b];
    float4 acc = make_float4(0.f, 0.f, 0.f, 0.f);
    #pragma unroll 4
    for (int it = 0; it < 16; ++it) {
        const int n = nbase + it * 16 + slot;
        const float w = sharp[bbase + n] * inv2;
        const float4 m4 = ((const float4*)(memory + (bbase + n) * 64))[m16];
        if (m16 == 0) rhead[bbase + n] = w;
        acc.x += w * m4.x; acc.y += w * m4.y; acc.z += w * m4.z; acc.w += w * m4.w;
    }
    for (int off = 32; off >= 16; off >>= 1) {
        acc.x += __shfl_xor(acc.x, off);
        acc.y += __shfl_xor(acc.y, off);
        acc.z += __shfl_xor(acc.z, off);
        acc.w += __shfl_xor(acc.w, off);
    }
    __shared__ float4 part[64];
    if (lane < 16) part[wid * 16 + lane] = acc;
    __syncthreads();
    if (tid < 16) {
        float4 t = part[tid];
        for (int w = 1; w < 4; ++w) {
            const float4 p = part[w * 16 + tid];
            t.x += p.x; t.y += p.y; t.z += p.z; t.w += p.w;
        }
        atomicAdd(&M_read[b * 64 + tid * 4 + 0], t.x);
        atomicAdd(&M_read[b * 64 + tid * 4 + 1], t.y);
        atomicAdd(&M_read[b * 64 + tid * 4 + 2], t.z);
        atomicAdd(&M_read[b * 64 + tid * 4 + 3], t.w);
    }
}

// ---------------------------------------------------------------------------
// K6: gates split-K GEMM (known-good baseline). Grid = 13*32 blocks.
// ---------------------------------------------------------------------------
__global__ __launch_bounds__(256) void gates_splitk_kernel(
    const float* __restrict__ inp,
    const float* __restrict__ M_read,
    const float* __restrict__ h_tm1,
    const float* __restrict__ W_ih,
    const float* __restrict__ W_hh,
    float* __restrict__ gates)
{
    __shared__ __align__(16) float Xsm[64][68];
    __shared__ __align__(16) float Wsm[64][68];
    const int tid = threadIdx.x;
    const int jb = blockIdx.x & 31;
    const int c  = blockIdx.x >> 5;      // K-chunk 0..12
    const int j0 = jb * 64;

    #pragma unroll
    for (int i = 0; i < 4; ++i) {
        const int e = i * 256 + tid;
        const int row = e >> 4;
        const int c4 = e & 15;
        const float* xrow;
        if (c < 4)       xrow = inp    + row * 256 + c * 64;
        else if (c == 4) xrow = M_read + row * 64;
        else             xrow = h_tm1  + row * 512 + (c - 5) * 64;
        const float4 v = ((const float4*)xrow)[c4];
        const int kl = c4 * 4;
        Xsm[kl + 0][row] = v.x; Xsm[kl + 1][row] = v.y;
        Xsm[kl + 2][row] = v.z; Xsm[kl + 3][row] = v.w;
    }
    #pragma unroll
    for (int i = 0; i < 4; ++i) {
        const int e = i * 256 + tid;
        const int row = e >> 4;
        const int c4 = e & 15;
        const float* wrow;
        if (c < 5) wrow = W_ih + (j0 + row) * 320 + c * 64;
        else       wrow = W_hh + (j0 + row) * 512 + (c - 5) * 64;
        const float4 v = ((const float4*)wrow)[c4];
        const int kl = c4 * 4;
        Wsm[kl + 0][row] = v.x; Wsm[kl + 1][row] = v.y;
        Wsm[kl + 2][row] = v.z; Wsm[kl + 3][row] = v.w;
    }
    __syncthreads();

    const int tx = tid & 15, ty = tid >> 4;
    float acc[4][4] = {};
    #pragma unroll
    for (int k = 0; k < 64; ++k) {
        const float4 av = *((const float4*)&Xsm[k][ty * 4]);
        const float4 wv = *((const float4*)&Wsm[k][tx * 4]);
        acc[0][0] += av.x * wv.x; acc[0][1] += av.x * wv.y; acc[0][2] += av.x * wv.z; acc[0][3] += av.x * wv.w;
        acc[1][0] += av.y * wv.x; acc[1][1] += av.y * wv.y; acc[1][2] += av.y * wv.z; acc[1][3] += av.y * wv.w;
        acc[2][0] += av.z * wv.x; acc[2][1] += av.z * wv.y; acc[2][2] += av.z * wv.z; acc[2][3] += av.z * wv.w;
        acc[3][0] += av.w * wv.x; acc[3][1] += av.w * wv.y; acc[3][2] += av.w * wv.z; acc[3][3] += av.w * wv.w;
    }
    #pragma unroll
    for (int bi = 0; bi < 4; ++bi) {
        const int b = ty * 4 + bi;
        #pragma unroll
        for (int ji = 0; ji < 4; ++ji) {
            atomicAdd(&gates[b * 2048 + j0 + tx * 4 + ji], acc[bi][ji]);
        }
    }
}

// ---------------------------------------------------------------------------
// K7: LSTM elementwise (biases folded in here).
// ---------------------------------------------------------------------------
__global__ __launch_bounds__(256) void lstm_kernel(
    const float* __restrict__ gates,
    const float* __restrict__ b_ih, const float* __restrict__ b_hh,
    const float* __restrict__ c_tm1,
    float* __restrict__ h_out, float* __restrict__ c_out)
{
    const int idx = blockIdx.x * 256 + threadIdx.x;  // B*H
    const int b = idx >> 9, j = idx & 511;
    const float* gr = gates + b * 2048;
    const float i_ = sigmoidf_(gr[j]        + b_ih[j]        + b_hh[j]);
    const float f_ = sigmoidf_(gr[512 + j]  + b_ih[512 + j]  + b_hh[512 + j]);
    const float g_ = tanhf(   gr[1024 + j] + b_ih[1024 + j] + b_hh[1024 + j]);
    const float o_ = sigmoidf_(gr[1536 + j] + b_ih[1536 + j] + b_hh[1536 + j]);
    const float c = f_ * c_tm1[idx] + i_ * g_;
    c_out[idx] = c;
    h_out[idx] = o_ * tanhf(c);
}

// ---------------------------------------------------------------------------
// K12: M_out = memory*(1 - w*e) + w*a, with w = sharpw[n]/ssum_w normalized
// here; whead final output also written here.
// ---------------------------------------------------------------------------
__global__ __launch_bounds__(256) void mout_norm_kernel(
    const float* __restrict__ memory,
    const float* __restrict__ sharpw,
    const float* __restrict__ ssum_w,
    const float* __restrict__ e,
    const float* __restrict__ a,
    float* __restrict__ whead,
    float* __restrict__ M_out)
{
    const size_t total = (size_t)B_ * N_ * 16;  // float4 count
    const size_t stride = (size_t)gridDim.x * 256;
    for (size_t idx = (size_t)blockIdx.x * 256 + threadIdx.x; idx < total; idx += stride) {
        const size_t nlin = idx >> 4;
        const int m4 = (int)(idx & 15);
        const int b = (int)(nlin >> 14);
        const float w = sharpw[nlin] * (1.f / ssum_w[b]);
        const float4 ev = ((const float4*)(e + b * 64))[m4];
        const float4 av = ((const float4*)(a + b * 64))[m4];
        const float4 mv = ((const float4*)memory)[idx];
        if (m4 == 0) whead[nlin] = w;   // same-wave: loads above precede this store
        float4 o;
        o.x = mv.x * (1.f - w * ev.x) + w * av.x;
        o.y = mv.y * (1.f - w * ev.y) + w * av.y;
        o.z = mv.z * (1.f - w * ev.z) + w * av.z;
        o.w = mv.w * (1.f - w * ev.w) + w * av.w;
        ((float4*)M_out)[idx] = o;
    }
}

// ---------------------------------------------------------------------------
extern "C" void kernel_launch(void* const* d_in, const int* in_sizes, int n_in,
                              void* d_out, int out_size, void* d_ws, size_t ws_size,
                              hipStream_t stream)
{
    const float* inp       = (const float*)d_in[0];
    const float* h_tm1     = (const float*)d_in[1];
    const float* c_tm1     = (const float*)d_in[2];
    const float* read_tm1  = (const float*)d_in[3];
    const float* write_tm1 = (const float*)d_in[4];
    const float* memory    = (const float*)d_in[5];
    const float* W_ih = (const float*)d_in[6];  const float* b_ih = (const float*)d_in[7];
    const float* W_hh = (const float*)d_in[8];  const float* b_hh = (const float*)d_in[9];
    const float* W_rk = (const float*)d_in[10]; const float* b_rk = (const float*)d_in[11];
    const float* W_wk = (const float*)d_in[12]; const float* b_wk = (const float*)d_in[13];
    const float* W_rc = (const float*)d_in[14]; const float* b_rc = (const float*)d_in[15];
    const float* W_wc = (const float*)d_in[16]; const float* b_wc = (const float*)d_in[17];
    const float* W_rs = (const float*)d_in[18]; const float* b_rs = (const float*)d_in[19];
    const float* W_ws = (const float*)d_in[20]; const float* b_ws = (const float*)d_in[21];
    const float* W_w  = (const float*)d_in[22]; const float* b_w  = (const float*)d_in[23];

    float* out = (float*)d_out;
    float* h_out = out;                       // B*H
    float* c_out = out + 32768;               // B*H
    float* rhead = out + 65536;               // B*N (final written by K5)
    float* whead = out + 65536 + 1048576;     // B*N (final written by K12)
    float* Mout  = out + 65536 + 2 * 1048576; // B*N*M (final written by K12)

    // Scratch aliased into output regions (each dead before final writer):
    float* x_r     = rhead;                   // K2 writes, K3/K4 read; K5 overwrites
    float* sharp_r = whead;                   // K4 writes, K5 reads
    float* x_w     = Mout;                    // K9 writes, K10/K11 read; K12 overwrites
    float* nMbuf   = Mout + (size_t)B_ * N_;  // K2 writes, K9 reads; K12 overwrites
    float* sharp_w = whead;                   // K11 writes (sharp_r dead), K12 reads

    // Workspace layout (floats); first 135296 floats zeroed in one memset:
    // gates 131072, M_read 4096, ssum_r 64, ssum_w 64.
    float* ws = (float*)d_ws;
    float* gates  = ws;
    float* M_read = ws + 131072;
    float* ssum_r = ws + 135168;
    float* ssum_w = ws + 135232;
    float* rk     = ws + 135296;
    float* wk     = ws + 139392;
    float* e_buf  = ws + 143488;
    float* a_buf  = ws + 147584;
    float* rs     = ws + 151680;
    float* wss    = ws + 151872;
    float* rbeta  = ws + 152064;
    float* rg     = ws + 152128;
    float* rgamma = ws + 152192;
    float* rnk    = ws + 152256;
    float* wbeta  = ws + 152320;
    float* wg     = ws + 152384;
    float* wgamma = ws + 152448;
    float* wnk    = ws + 152512;
    float* gmax_r = ws + 152576;
    float* ginv_r = ws + 152640;
    float* gmax_w = ws + 152704;
    float* ginv_w = ws + 152768;

    hipMemsetAsync(gates, 0, (131072 + 4096 + 64 + 64) * sizeof(float), stream);

    // ---- read head ----
    head_params_kernel<false><<<B_, 256, 0, stream>>>(
        h_tm1, W_rk, b_rk, W_rc, b_rc, W_rs, b_rs, nullptr, nullptr,
        rk, rnk, rs, rbeta, rg, rgamma, nullptr, nullptr);
    score_kernel<0><<<B_ * 256, 256, 0, stream>>>(memory, rk, rbeta, rnk, x_r, nMbuf);
    softmax_stats_kernel<<<B_, 1024, 0, stream>>>(x_r, gmax_r, ginv_r);
    conv_sharp_kernel<<<B_ * 64, 256, 0, stream>>>(
        x_r, read_tm1, gmax_r, ginv_r, rg, rgamma, rs, sharp_r, ssum_r);
    mread_norm_kernel<<<B_ * 64, 256, 0, stream>>>(memory, sharp_r, ssum_r, rhead, M_read);

    // ---- LSTM ----
    gates_splitk_kernel<<<13 * 32, 256, 0, stream>>>(inp, M_read, h_tm1, W_ih, W_hh, gates);
    lstm_kernel<<<128, 256, 0, stream>>>(gates, b_ih, b_hh, c_tm1, h_out, c_out);

    // ---- write head ----
    head_params_kernel<true><<<B_, 256, 0, stream>>>(
        h_out, W_wk, b_wk, W_wc, b_wc, W_ws, b_ws, W_w, b_w,
        wk, wnk, wss, wbeta, wg, wgamma, e_buf, a_buf);
    score_kernel<1><<<B_ * 256, 256, 0, stream>>>(memory, wk, wbeta, wnk, x_w, nMbuf);
    softmax_stats_kernel<<<B_, 1024, 0, stream>>>(x_w, gmax_w, ginv_w);
    conv_sharp_kernel<<<B_ * 64, 256, 0, stream>>>(
        x_w, write_tm1, gmax_w, ginv_w, wg, wgamma, wss, sharp_w, ssum_w);
    mout_norm_kernel<<<16384, 256, 0, stream>>>(
        memory, sharp_w, ssum_w, e_buf, a_buf, whead, Mout);
}